// Round 4
// baseline (231.309 us; speedup 1.0000x reference)
//
#include <hip/hip_runtime.h>
#include <hip/hip_bf16.h>

#define NB    4096   // batch rows
#define NK    4      // modalities
#define ND    1024   // d_in
#define NH    1024   // hidden out
#define NCTX  256
#define NRH   64

typedef float f32x4 __attribute__((ext_vector_type(4)));
typedef float f32x8 __attribute__((ext_vector_type(8)));
typedef short s16x8 __attribute__((ext_vector_type(8)));
typedef _Float16 f16x8 __attribute__((ext_vector_type(8)));

__device__ __forceinline__ void gl_lds16(const void* g, void* l) {
    __builtin_amdgcn_global_load_lds(
        (const __attribute__((address_space(1))) unsigned int*)g,
        (__attribute__((address_space(3))) unsigned int*)l, 16, 0, 0);
}

// ---------------------------------------------------------------------------
// Kernel 1: router MLP -> gates[B][K] = (mask>0.5)*mask*softmax(fusion_w)[k]
// ---------------------------------------------------------------------------
__global__ __launch_bounds__(256) void router_k(
    const float* __restrict__ ctx, const float* __restrict__ gum,
    const float* __restrict__ W1, const float* __restrict__ b1,
    const float* __restrict__ gln, const float* __restrict__ bln,
    const float* __restrict__ W2, const float* __restrict__ b2,
    const float* __restrict__ W3, const float* __restrict__ b3,
    const float* __restrict__ prior, const float* __restrict__ fw,
    float* __restrict__ gates)
{
    __shared__ float sH[4][4][64];
    __shared__ float sH2[4][4][32];

    const int tid  = threadIdx.x;
    const int w    = tid >> 6;
    const int lane = tid & 63;
    const int rowbase = blockIdx.x * 16 + w * 4;
    const int rbu = __builtin_amdgcn_readfirstlane(rowbase);
    const float* c0 = ctx + (size_t)rbu * NCTX;

    float a0 = 0.f, a1 = 0.f, a2 = 0.f, a3 = 0.f;
#pragma unroll 8
    for (int d = 0; d < NCTX; ++d) {
        float wv = W1[d * NRH + lane];
        a0 = fmaf(c0[d],          wv, a0);
        a1 = fmaf(c0[NCTX + d],   wv, a1);
        a2 = fmaf(c0[2*NCTX + d], wv, a2);
        a3 = fmaf(c0[3*NCTX + d], wv, a3);
    }
    const float bb = b1[lane];
    float hr[4] = {a0 + bb, a1 + bb, a2 + bb, a3 + bb};
    const float gl = gln[lane], be = bln[lane];

#pragma unroll
    for (int r = 0; r < 4; ++r) {
        float h = hr[r];
        float s = h;
#pragma unroll
        for (int m = 32; m >= 1; m >>= 1) s += __shfl_xor(s, m);
        float mu = s * (1.f / 64.f);
        float dd = h - mu;
        float q = dd * dd;
#pragma unroll
        for (int m = 32; m >= 1; m >>= 1) q += __shfl_xor(q, m);
        float var = q * (1.f / 64.f);
        h = dd * rsqrtf(var + 1e-5f) * gl + be;
        sH[w][r][lane] = fmaxf(h, 0.f);
    }

#pragma unroll
    for (int p = 0; p < 2; ++p) {
        const int r = p * 2 + (lane >> 5);
        const int j = lane & 31;
        float acc = b2[j];
#pragma unroll 8
        for (int l = 0; l < 64; ++l)
            acc = fmaf(sH[w][r][l], W2[l * 32 + j], acc);
        sH2[w][r][j] = fmaxf(acc, 0.f);
    }

    const int r3 = lane >> 2, j3 = lane & 3;
    float lg = 0.f;
    if (lane < 16) {
        lg = b3[j3] + prior[j3];
#pragma unroll 8
        for (int l = 0; l < 32; ++l)
            lg = fmaf(sH2[w][r3][l], W3[l * 4 + j3], lg);
    }
    float pj = 1.f / (1.f + expf(-lg));
    const int base = lane & 60;
    float P0 = __shfl(pj, base), P1 = __shfl(pj, base | 1);
    float P2 = __shfl(pj, base | 2), P3 = __shfl(pj, base | 3);

    if (lane < 16) {
        float f0 = fw[0], f1 = fw[1], f2 = fw[2], f3 = fw[3];
        float fm = fmaxf(fmaxf(f0, f1), fmaxf(f2, f3));
        float e0 = expf(f0 - fm), e1 = expf(f1 - fm), e2 = expf(f2 - fm), e3 = expf(f3 - fm);
        float es = e0 + e1 + e2 + e3;
        float wsm = (j3 == 0 ? e0 : j3 == 1 ? e1 : j3 == 2 ? e2 : e3) / es;

        int cnt = 0;
        cnt += (P0 > pj) || ((P0 == pj) && (0 < j3));
        cnt += (P1 > pj) || ((P1 == pj) && (1 < j3));
        cnt += (P2 > pj) || ((P2 == pj) && (2 < j3));
        cnt += (P3 > pj) || ((P3 == pj) && (3 < j3));

        const int row = rowbase + r3;
        float soft = 1.f / (1.f + expf(-(lg + gum[row * 4 + j3])));
        float mask = (cnt < 2) ? 1.0f : soft;
        float gate = (mask > 0.5f) ? mask * wsm : 0.0f;
        gates[row * 4 + j3] = gate;
    }
}

// ---------------------------------------------------------------------------
// Kernel 2: W_enc [K][D][H] fp32 -> Bh f16 [K][H][D] (transpose + f16 cast)
// ---------------------------------------------------------------------------
__global__ __launch_bounds__(256) void wprep_k(
    const float* __restrict__ W, unsigned short* __restrict__ whi)
{
    __shared__ float sT[32][33];
    const int bid = blockIdx.x;
    const int k  = bid >> 10;
    const int dt = (bid >> 5) & 31;
    const int ht = bid & 31;
    const int t = threadIdx.x;
    {
        const int r  = t >> 3;
        const int c4 = (t & 7) << 2;
        const float* src = W + ((size_t)k << 20) + (size_t)(dt * 32 + r) * 1024 + (ht * 32 + c4);
        float4 v = *(const float4*)src;
        sT[c4 + 0][r] = v.x; sT[c4 + 1][r] = v.y;
        sT[c4 + 2][r] = v.z; sT[c4 + 3][r] = v.w;
    }
    __syncthreads();
    {
        const int h  = t >> 3;
        const int d4 = (t & 7) << 2;
        unsigned short uh[4];
#pragma unroll
        for (int q = 0; q < 4; ++q) {
            _Float16 hi = (_Float16)sT[h][d4 + q];
            uh[q] = __builtin_bit_cast(unsigned short, hi);
        }
        size_t o = ((size_t)k << 20) + (size_t)(ht * 32 + h) * 1024 + (dt * 32 + d4);
        *(ushort4*)(whi + o) = make_ushort4(uh[0], uh[1], uh[2], uh[3]);
    }
}

// ---------------------------------------------------------------------------
// Kernel 3: A-prep: Ah[b][ks*1024+d] = f16(x[ks,b,d] * gates[b,ks])
// ---------------------------------------------------------------------------
__global__ __launch_bounds__(256) void aprep_k(
    const float* __restrict__ x, const float* __restrict__ gates,
    unsigned short* __restrict__ Ah)
{
    const int bid = blockIdx.x;
    const int k  = bid >> 11;          // 0..3
    const int bp = bid & 2047;         // b pair
    const int t = threadIdx.x;
    const int boff = t >> 7;
    const int d8 = (t & 127) << 3;
    const int b = bp * 2 + boff;
    const float g = gates[b * 4 + k];

    f32x8 v = *(const f32x8*)(x + ((size_t)k << 22) + (size_t)b * ND + d8);
    v *= g;
    f16x8 hb = __builtin_convertvector(v, f16x8);
    const size_t o = (size_t)b * 4096 + (k << 10) + d8;
    *(s16x8*)(Ah + o) = __builtin_bit_cast(s16x8, hb);
}

// ---------------------------------------------------------------------------
// Kernel 4: zero-init out (graph-capture-safe memset)
// ---------------------------------------------------------------------------
__global__ __launch_bounds__(256) void zero_k(float* __restrict__ out)
{
    const size_t i = ((size_t)blockIdx.x * 256 + threadIdx.x) * 8;
    *(f32x8*)(out + i) = (f32x8){0.f,0.f,0.f,0.f,0.f,0.f,0.f,0.f};
}

// ---------------------------------------------------------------------------
// Kernel 5: single-pass f16 MFMA GEMM, K-split 2x, atomic-accumulate epilogue.
// out += Ah·Bh (+ bias on ksp==0 half).  M=4096 N=1024 K=4096 (2x K=2048).
// BM=128 BN=128 BK=64; 4 waves 2x2 (wave tile 64x64 -> ds_read:MFMA = 1:2);
// grid 512 (2 blk/CU).  LDS 32KB single-buffered, 2 barriers/tile (R2's
// winning structure).  T2 XOR-swizzle via pre-swizzled global src (rule 21).
// ---------------------------------------------------------------------------
__global__ __launch_bounds__(256, 2) void gemm_k(
    const unsigned short* __restrict__ Ahg,
    const unsigned short* __restrict__ Bhg,
    const float* __restrict__ gates, const float* __restrict__ benc,
    float* __restrict__ out)
{
    __shared__ unsigned short sA[128 * 64];
    __shared__ unsigned short sB[128 * 64];

    const int bid = blockIdx.x;
    const int wg  = (bid & 7) * 64 + (bid >> 3);   // XCD-grouped, bijective
    const int ksp = wg >> 8;               // K-split half: 0/1
    const int rem = wg & 255;
    const int bm  = rem >> 3;              // 0..31
    const int bn  = rem & 7;               // 0..7

    const int tid = threadIdx.x;
    const int wv  = tid >> 6, ln = tid & 63;
    const int wr  = wv >> 1,  wc = wv & 1;
    const int l15 = ln & 15,  ls = ln >> 4;
    const int rowb = bm * 128;
    const int colb = bn * 128;

    // staging: LDS byte L = chunk*1024 + l*16 holds (row = L>>7,
    // col_bytes = (L&127) ^ ((row&7)<<4)); row = chunk*8 + (l>>3)
    const int srow = ln >> 3;
    const int slot = (ln & 7) ^ srow;
    size_t aoff[4], boff[4];
#pragma unroll
    for (int i = 0; i < 4; ++i) {
        const int row = (wv * 4 + i) * 8 + srow;
        aoff[i] = (size_t)(rowb + row) * 4096 + slot * 8;   // + kflat
        boff[i] = (size_t)(colb + row) * 1024 + slot * 8;   // + (ksmod<<20)+dbase
    }

    const int arow0 = (wr * 64 + l15) * 128;
    const int brow0 = (wc * 64 + l15) * 128;
    const int xr = (l15 & 7) << 4;
    int colswz[2];
#pragma unroll
    for (int kk = 0; kk < 2; ++kk)
        colswz[kk] = ((kk << 6) + (ls << 4)) ^ xr;

    f32x4 acc[4][4];
#pragma unroll
    for (int a = 0; a < 4; ++a)
#pragma unroll
        for (int b = 0; b < 4; ++b)
            acc[a][b] = (f32x4){0.f, 0.f, 0.f, 0.f};

#pragma unroll 1
    for (int kt = 0; kt < 32; ++kt) {
        const int kflat = ksp * 2048 + kt * 64;
        const size_t wk = ((size_t)(kflat >> 10) << 20) + (size_t)(kflat & 1023);

        // ---- stage 32KB (4 A-chunks + 4 B-chunks per thread)
#pragma unroll
        for (int i = 0; i < 4; ++i) {
            const int chunk = wv * 4 + i;
            gl_lds16(Ahg + aoff[i] + kflat, &sA[chunk * 512]);
            gl_lds16(Bhg + boff[i] + wk,    &sB[chunk * 512]);
        }
        __syncthreads();   // vmcnt(0)+lgkmcnt(0) drain + barrier

        // ---- compute: 2 k-substeps of 32; 8 ds_read_b128 : 16 MFMA each
#pragma unroll
        for (int kk = 0; kk < 2; ++kk) {
            f16x8 af[4], bf[4];
#pragma unroll
            for (int mi = 0; mi < 4; ++mi)
                af[mi] = __builtin_bit_cast(f16x8,
                    *(const s16x8*)((const char*)sA + arow0 + mi * 2048 + colswz[kk]));
#pragma unroll
            for (int ni = 0; ni < 4; ++ni)
                bf[ni] = __builtin_bit_cast(f16x8,
                    *(const s16x8*)((const char*)sB + brow0 + ni * 2048 + colswz[kk]));
#pragma unroll
            for (int mi = 0; mi < 4; ++mi)
#pragma unroll
                for (int ni = 0; ni < 4; ++ni)
                    acc[mi][ni] = __builtin_amdgcn_mfma_f32_16x16x32_f16(
                        af[mi], bf[ni], acc[mi][ni], 0, 0, 0);
        }
        __syncthreads();
    }

    // ---- epilogue: atomic-accumulate; ksp==0 half also adds the gated bias.
    // C/D frag: col=l&15, row=(l>>4)*4+j
    float bce[4][4];
    if (ksp == 0) {
#pragma unroll
        for (int ni = 0; ni < 4; ++ni) {
            const int col = colb + wc * 64 + ni * 16 + l15;
#pragma unroll
            for (int kk = 0; kk < 4; ++kk)
                bce[ni][kk] = benc[kk * NH + col];
        }
    }
#pragma unroll
    for (int mi = 0; mi < 4; ++mi) {
#pragma unroll
        for (int j = 0; j < 4; ++j) {
            const int row = rowb + wr * 64 + mi * 16 + ls * 4 + j;
            const float4 g = *(const float4*)(gates + row * 4);
#pragma unroll
            for (int ni = 0; ni < 4; ++ni) {
                const int col = colb + wc * 64 + ni * 16 + l15;
                float val = acc[mi][ni][j];
                if (ksp == 0)
                    val += g.x * bce[ni][0] + g.y * bce[ni][1] +
                           g.z * bce[ni][2] + g.w * bce[ni][3];
                unsafeAtomicAdd(out + (size_t)row * NH + col, val);
            }
        }
    }
}

// ---------------------------------------------------------------------------
extern "C" void kernel_launch(void* const* d_in, const int* in_sizes, int n_in,
                              void* d_out, int out_size, void* d_ws, size_t ws_size,
                              hipStream_t stream)
{
    const float* ctx   = (const float*)d_in[0];
    const float* x     = (const float*)d_in[1];
    const float* gum   = (const float*)d_in[2];
    const float* W1    = (const float*)d_in[3];
    const float* b1    = (const float*)d_in[4];
    const float* gln   = (const float*)d_in[5];
    const float* bln   = (const float*)d_in[6];
    const float* W2    = (const float*)d_in[7];
    const float* b2    = (const float*)d_in[8];
    const float* W3    = (const float*)d_in[9];
    const float* b3    = (const float*)d_in[10];
    const float* prior = (const float*)d_in[11];
    const float* Wenc  = (const float*)d_in[12];
    const float* benc  = (const float*)d_in[13];
    const float* fw    = (const float*)d_in[14];
    float* out = (float*)d_out;

    // ws layout: gates 64KB | Bh 8MB | Ah 32MB  (~40.1MB)
    char* ws = (char*)d_ws;
    float* gates        = (float*)ws;
    unsigned short* bh  = (unsigned short*)(ws + (64 << 10));
    unsigned short* ah  = (unsigned short*)(ws + (64 << 10) + (8ull << 20));

    hipLaunchKernelGGL(router_k, dim3(256), dim3(256), 0, stream,
                       ctx, gum, W1, b1, gln, bln, W2, b2, W3, b3, prior, fw, gates);
    hipLaunchKernelGGL(aprep_k, dim3(8192), dim3(256), 0, stream, x, gates, ah);
    hipLaunchKernelGGL(wprep_k, dim3(4096), dim3(256), 0, stream, Wenc, bh);
    hipLaunchKernelGGL(zero_k, dim3(2048), dim3(256), 0, stream, out);
    hipLaunchKernelGGL(gemm_k, dim3(512), dim3(256), 0, stream,
                       ah, bh, gates, benc, out);
}